// Round 17
// baseline (54.480 us; speedup 1.0000x reference)
//
#include <hip/hip_runtime.h>
#include <math.h>

#define B 128
#define S 32
#define Dm 128
#define NV (B * S)
#define MARGINF 0.3f
#define NTILE 528   // 32 groups of 4 tracklets: 32*33/2 group-pair tiles

// exp2 pre-scaling: exp(sqrt(d2)) == 2^(sqrt(d2*K2))
#define K2F 2.0813689810056077f   // (log2 e)^2
#define C2F 4.1627379620112154f   // 2*K2
#define EPS2 2.081368981e-12f     // K2 * 1e-12

typedef __attribute__((ext_vector_type(8))) short short8;
typedef __attribute__((ext_vector_type(16))) float f32x16;

#define GLOBAL_AS __attribute__((address_space(1)))
#define LDS_AS __attribute__((address_space(3)))

#define FSQRT(x) __builtin_amdgcn_sqrtf(x)   // raw v_sqrt_f32 (~1 ulp)

__device__ inline float exp2raw(float x) {   // raw v_exp_f32: D = 2^S0
    float r;
    asm("v_exp_f32 %0, %1" : "=v"(r) : "v"(x));
    return r;
}

// RNE f32 -> bf16 (finite inputs only)
__device__ inline unsigned short f2bf(float f) {
    unsigned u = __float_as_uint(f);
    unsigned r = u + 0x7FFF + ((u >> 16) & 1);
    return (unsigned short)(r >> 16);
}
__device__ inline float bf2f(unsigned short h) {
    return __uint_as_float(((unsigned)h) << 16);
}

// ---------------------------------------------------------------------------
// K1 (prep): one block per tracklet i. Normalize, quantize to bf16, write Zn
// (linear) + swizzled LDS copy; sqv = |z|^2 * K2F (pre-scaled for the exp2
// path), from the QUANTIZED z. Wave 0 computes diagsum[i][p] via MFMA.
// ---------------------------------------------------------------------------
__global__ __launch_bounds__(256) void prep_kernel(const float* __restrict__ X,
                                                   unsigned short* __restrict__ Zn,
                                                   float* __restrict__ sqv,
                                                   float* __restrict__ diagsum) {
    int i = blockIdx.x;
    __shared__ unsigned short zlds[4096];   // 32 rows x 128 bf16, swizzled
    __shared__ float sq_sh[32];             // scaled by K2F
    int t = threadIdx.x;

    int v = t >> 3;          // vector 0..31
    int s = t & 7;           // 8 lanes per vector
    const float4* row = (const float4*)(X + (((size_t)i * S + v) << 7));

    float4 f[4];
    float ss = 0.f;
#pragma unroll
    for (int k = 0; k < 4; ++k) {
        f[k] = row[k * 8 + s];
        ss += f[k].x * f[k].x + f[k].y * f[k].y + f[k].z * f[k].z + f[k].w * f[k].w;
    }
    ss += __shfl_xor(ss, 1); ss += __shfl_xor(ss, 2); ss += __shfl_xor(ss, 4);
    float inv = 1.0f / fmaxf(FSQRT(ss), 1e-12f);

    float s2 = 0.f;
    unsigned short* zrow = Zn + (((size_t)i * S + v) << 7);
#pragma unroll
    for (int k = 0; k < 4; ++k) {
        int fidx = k * 8 + s;              // float4 index within the row (0..31)
        ushort4 h;
        h.x = f2bf(f[k].x * inv); h.y = f2bf(f[k].y * inv);
        h.z = f2bf(f[k].z * inv); h.w = f2bf(f[k].w * inv);
        float gx = bf2f(h.x), gy = bf2f(h.y), gz = bf2f(h.z), gw = bf2f(h.w);
        s2 += gx * gx + gy * gy + gz * gz + gw * gw;
        *(ushort4*)(zrow + fidx * 4) = h;  // global: linear
        // LDS: 16B chunk c = fidx>>1 goes to slot c^(v&7); 8B half = fidx&1
        int addr = (v << 8) + ((((fidx >> 1) ^ (v & 7))) << 4) + ((fidx & 1) << 3);
        *(ushort4*)((char*)zlds + addr) = h;
    }
    s2 += __shfl_xor(s2, 1); s2 += __shfl_xor(s2, 2); s2 += __shfl_xor(s2, 4);
    float s2s = s2 * K2F;
    if (s == 0) { sqv[(i << 5) + v] = s2s; sq_sh[v] = s2s; }
    __syncthreads();

    if (t < 64) {   // wave 0: E_ii row sums
        int lq = t & 31, kh = t >> 5, sx = lq & 7;
        f32x16 acc;
#pragma unroll
        for (int r = 0; r < 16; ++r) acc[r] = 0.f;
#pragma unroll
        for (int ks = 0; ks < 8; ++ks) {
            int off = (lq << 8) + (((2 * ks + kh) ^ sx) << 4);
            short8 av = *(const short8*)((char*)zlds + off);
            acc = __builtin_amdgcn_mfma_f32_32x32x16_bf16(av, av, acc, 0, 0, 0);
        }
        float sql = sq_sh[lq];
        float ssum = 0.f;
#pragma unroll
        for (int r = 0; r < 16; ++r) {
            int m = (r & 3) + 8 * (r >> 2) + 4 * kh;
            float d2 = fmaxf(sq_sh[m] + sql - C2F * acc[r], EPS2);
            ssum += exp2raw(FSQRT(d2));
        }
        ssum += __shfl_xor(ssum, 32);
        if (t < 32) diagsum[(i << 5) + lq] = ssum;
    }
}

// ---------------------------------------------------------------------------
// K2 (pair): 4x4 group tiles, ONE WAVE PER PAIR. Tile t0 -> (ig <= jg) via
// triangular unranking. Stages 8 panels (4 i + 4 j, 64 KB) via
// global_load_lds (linear LDS dest, XOR swizzle on the per-lane GLOBAL
// source; same involution on the ds_read side). 1024 threads = 16 waves;
// wave w owns pair (i = 4ig + (w>>2), j = 4jg + (w&3)), active iff j > i
// (off-diag tiles: all 16 active; diag tiles: 6 active). Dual MFMA
// (acc = Zi.Zj^T col stats in-lane; acc2 = Zj.Zi^T row stats in-lane),
// slimmed exp2 epilogue, bitonic rank-select -> Dmat[i][j] = Dmat[j][i].
// 2 blocks/CU x 16 waves = 32 waves/CU (max); 528 blocks ~ 1.03 generations.
// __launch_bounds__(1024, 8) pins VGPR <= 64 so both blocks fit per CU.
// ---------------------------------------------------------------------------
__global__ __launch_bounds__(1024, 8) void pair_kernel(const unsigned short* __restrict__ Zn,
                                                       const float* __restrict__ sqv,
                                                       const float* __restrict__ diagsum,
                                                       const int* __restrict__ tgt,
                                                       float* __restrict__ Dmat) {
    // unrank t0 -> (ig, jg), ig <= jg: t0 = jg*(jg+1)/2 + ig
    int t0 = blockIdx.x;
    int jg = (int)((sqrtf(8.f * (float)t0 + 1.f) - 1.f) * 0.5f);
    while (jg > 0 && t0 < jg * (jg + 1) / 2) --jg;
    while (t0 >= (jg + 1) * (jg + 2) / 2) ++jg;
    int ig = t0 - jg * (jg + 1) / 2;

    extern __shared__ unsigned short lds[];   // 8 * 4096 ushort = 64 KB

    int t = threadIdx.x;
    int w = t >> 6;          // 0..15
    int lane = t & 63;
    int slot = lane & 15;
    int rhi = lane >> 4;

    // ---- staging: 64 segs of 1 KB; wave w owns segs [w*4, w*4+4) ----
#pragma unroll
    for (int k = 0; k < 4; ++k) {
        int seg = w * 4 + k;
        int panel = seg >> 3;              // 0..7
        int row = ((seg & 7) << 2) | rhi;  // 0..31
        int vec = (panel < 4) ? (ig * 4 + panel) : (jg * 4 + panel - 4);
        const unsigned short* gsrc =
            Zn + ((size_t)vec << 12) + (row << 7) + ((slot ^ (row & 7)) << 3);
        unsigned short* ldst = lds + seg * 512;
        __builtin_amdgcn_global_load_lds((const GLOBAL_AS void*)(const void*)gsrc,
                                         (LDS_AS void*)(void*)ldst, 16, 0, 0);
    }
    __syncthreads();

    int i = ig * 4 + (w >> 2);
    int j = jg * 4 + (w & 3);
    if (j <= i) return;       // idle waves on diagonal tiles; no more barriers

    const unsigned short* Pi = lds + (w >> 2) * 4096;
    const unsigned short* Pj = lds + (4 + (w & 3)) * 4096;
    int lq = lane & 31;
    int kh = lane >> 5;
    int sx = lq & 7;

    f32x16 acc, acc2;
#pragma unroll
    for (int r = 0; r < 16; ++r) { acc[r] = 0.f; acc2[r] = 0.f; }

#pragma unroll
    for (int ks = 0; ks < 8; ++ks) {
        int off = (lq << 7) + (((2 * ks + kh) ^ sx) << 3);
        short8 av = *(const short8*)(Pi + off);
        short8 bv = *(const short8*)(Pj + off);
        acc  = __builtin_amdgcn_mfma_f32_32x32x16_bf16(av, bv, acc, 0, 0, 0);
        acc2 = __builtin_amdgcn_mfma_f32_32x32x16_bf16(bv, av, acc2, 0, 0, 0);
    }

    // ---- slimmed epilogue ----
    float sqi_l = sqv[(i << 5) + lq];      // pre-scaled by K2F
    float sqj_l = sqv[(j << 5) + lq];
    float di = diagsum[(i << 5) + lq];
    float dj = diagsum[(j << 5) + lq];

    float sab[16], sba[16];
#pragma unroll
    for (int r = 0; r < 16; ++r) {
        int m = (r & 3) + 8 * (r >> 2) + 4 * kh;
        sab[r] = __shfl(sqi_l, m) + sqj_l;
        sba[r] = __shfl(sqj_l, m) + sqi_l;
    }

    float csum = 0.f, cmin = INFINITY, rsum = 0.f, rmin = INFINITY;
#pragma unroll
    for (int r = 0; r < 16; ++r) {
        float d2a = fmaxf(sab[r] - C2F * acc[r], EPS2);    // E[m][lq]
        float ea = exp2raw(FSQRT(d2a));
        csum += ea; cmin = fminf(cmin, ea);
        float d2b = fmaxf(sba[r] - C2F * acc2[r], EPS2);   // E[lq][m]
        float eb = exp2raw(FSQRT(d2b));
        rsum += eb; rmin = fminf(rmin, eb);
    }
    csum += __shfl_xor(csum, 32);
    cmin = fminf(cmin, __shfl_xor(cmin, 32));
    rsum += __shfl_xor(rsum, 32);
    rmin = fminf(rmin, __shfl_xor(rmin, 32));

    float aval = rmin / (di + rsum);
    float cval = cmin / (dj + csum);

    // bitonic ascending sort per 32-lane half: half0 = a, half1 = c
    float v = (lane < 32) ? aval : cval;
#pragma unroll
    for (int k = 2; k <= 32; k <<= 1) {
#pragma unroll
        for (int mm = k >> 1; mm >= 1; mm >>= 1) {
            float o = __shfl_xor(v, mm);
            bool asc = ((lq & k) == 0);
            bool upper = (lq & mm) != 0;
            float mn = fminf(v, o), mx = fmaxf(v, o);
            v = (asc == upper) ? mx : mn;
        }
    }
    // ascending: 3rd largest at lane 29, 6th at lane 26 (per half)
    float ta3 = __shfl(v, 29), ta6 = __shfl(v, 26);
    float tc3 = __shfl(v, 61), tc6 = __shfl(v, 58);

    if (lane == 0) {
        float v_same = fmaxf(ta6, tc6);
        float v_diff = fminf(ta3, tc3);
        float val = (tgt[i] == tgt[j]) ? v_same : v_diff;
        Dmat[i * B + j] = val;
        Dmat[j * B + i] = val;
    }
}

// ---------------------------------------------------------------------------
// K3 (final): 1024 threads; 8 threads per row i scan 16 cols each, reduce
// via shfl, then block-reduce the 128 row terms.
// ---------------------------------------------------------------------------
__global__ __launch_bounds__(1024) void final_kernel(const float* __restrict__ Dmat,
                                                     const int* __restrict__ tgt,
                                                     float* __restrict__ out) {
    int t = threadIdx.x;
    int i = t >> 3;          // row 0..127
    int c = t & 7;           // col chunk
    int ti = tgt[i];
    float ap = -INFINITY, an = INFINITY;
#pragma unroll
    for (int k = 0; k < 16; ++k) {
        int jj = c * 16 + k;
        float v = (jj == i) ? 0.f : Dmat[jj * B + i];   // D symmetric
        if (tgt[jj] == ti) ap = fmaxf(ap, v);
        else an = fminf(an, v);
    }
    ap = fmaxf(ap, __shfl_xor(ap, 1)); an = fminf(an, __shfl_xor(an, 1));
    ap = fmaxf(ap, __shfl_xor(ap, 2)); an = fminf(an, __shfl_xor(an, 2));
    ap = fmaxf(ap, __shfl_xor(ap, 4)); an = fminf(an, __shfl_xor(an, 4));

    __shared__ float red[128];
    if (c == 0) {
        float term = ap - an + MARGINF;
        red[i] = term > 0.f ? term : 0.f;
    }
    __syncthreads();
    if (t < 64) {
        float r0 = red[t] + red[t + 64];
        r0 += __shfl_down(r0, 32); r0 += __shfl_down(r0, 16);
        r0 += __shfl_down(r0, 8);  r0 += __shfl_down(r0, 4);
        r0 += __shfl_down(r0, 2);  r0 += __shfl_down(r0, 1);
        if (t == 0) out[0] = r0 / (float)B;
    }
}

// ---------------------------------------------------------------------------
extern "C" void kernel_launch(void* const* d_in, const int* in_sizes, int n_in,
                              void* d_out, int out_size, void* d_ws, size_t ws_size,
                              hipStream_t stream) {
    const float* X = (const float*)d_in[0];   // (128, 32, 128) f32
    const int* tgt = (const int*)d_in[1];     // (128,) int
    float* out = (float*)d_out;

    // ws: Zn bf16 1MB | sqv 16KB | diagsum 16KB | Dmat 64KB
    unsigned short* Zn = (unsigned short*)d_ws;
    float* sqv = (float*)(Zn + (size_t)NV * Dm);
    float* diagsum = sqv + NV;
    float* Dmat = diagsum + NV;

    prep_kernel<<<B, 256, 0, stream>>>(X, Zn, sqv, diagsum);
    pair_kernel<<<NTILE, 1024, 8 * 4096 * sizeof(unsigned short), stream>>>(
        Zn, sqv, diagsum, tgt, Dmat);
    final_kernel<<<1, 1024, 0, stream>>>(Dmat, tgt, out);
}

// Round 18
// 31.418 us; speedup vs baseline: 1.7340x; 1.7340x over previous
//
#include <hip/hip_runtime.h>
#include <math.h>

#define B 128
#define S 32
#define Dm 128
#define NV (B * S)
#define MARGINF 0.3f
#define NTILE 1056   // sum over jg=0..31 of (2*jg+2)

// exp2 pre-scaling: exp(sqrt(d2)) == 2^(sqrt(d2*K2))
#define K2F 2.0813689810056077f   // (log2 e)^2
#define C2F 4.1627379620112154f   // 2*K2
#define EPS2 2.081368981e-12f     // K2 * 1e-12

typedef __attribute__((ext_vector_type(8))) short short8;
typedef __attribute__((ext_vector_type(16))) float f32x16;

#define GLOBAL_AS __attribute__((address_space(1)))
#define LDS_AS __attribute__((address_space(3)))

#define FSQRT(x) __builtin_amdgcn_sqrtf(x)   // raw v_sqrt_f32 (~1 ulp)

__device__ inline float exp2raw(float x) {   // raw v_exp_f32: D = 2^S0
    float r;
    asm("v_exp_f32 %0, %1" : "=v"(r) : "v"(x));
    return r;
}

// RNE f32 -> bf16 (finite inputs only)
__device__ inline unsigned short f2bf(float f) {
    unsigned u = __float_as_uint(f);
    unsigned r = u + 0x7FFF + ((u >> 16) & 1);
    return (unsigned short)(r >> 16);
}
__device__ inline float bf2f(unsigned short h) {
    return __uint_as_float(((unsigned)h) << 16);
}

// ---------------------------------------------------------------------------
// K1 (prep): one block per tracklet i. Normalize, quantize to bf16, write Zn
// (linear) + swizzled LDS copy; sqv = |z|^2 * K2F (pre-scaled for the exp2
// path), from the QUANTIZED z. Wave 0 computes diagsum[i][p] via MFMA.
// ---------------------------------------------------------------------------
__global__ __launch_bounds__(256) void prep_kernel(const float* __restrict__ X,
                                                   unsigned short* __restrict__ Zn,
                                                   float* __restrict__ sqv,
                                                   float* __restrict__ diagsum) {
    int i = blockIdx.x;
    __shared__ unsigned short zlds[4096];   // 32 rows x 128 bf16, swizzled
    __shared__ float sq_sh[32];             // scaled by K2F
    int t = threadIdx.x;

    int v = t >> 3;          // vector 0..31
    int s = t & 7;           // 8 lanes per vector
    const float4* row = (const float4*)(X + (((size_t)i * S + v) << 7));

    float4 f[4];
    float ss = 0.f;
#pragma unroll
    for (int k = 0; k < 4; ++k) {
        f[k] = row[k * 8 + s];
        ss += f[k].x * f[k].x + f[k].y * f[k].y + f[k].z * f[k].z + f[k].w * f[k].w;
    }
    ss += __shfl_xor(ss, 1); ss += __shfl_xor(ss, 2); ss += __shfl_xor(ss, 4);
    float inv = 1.0f / fmaxf(FSQRT(ss), 1e-12f);

    float s2 = 0.f;
    unsigned short* zrow = Zn + (((size_t)i * S + v) << 7);
#pragma unroll
    for (int k = 0; k < 4; ++k) {
        int fidx = k * 8 + s;              // float4 index within the row (0..31)
        ushort4 h;
        h.x = f2bf(f[k].x * inv); h.y = f2bf(f[k].y * inv);
        h.z = f2bf(f[k].z * inv); h.w = f2bf(f[k].w * inv);
        float gx = bf2f(h.x), gy = bf2f(h.y), gz = bf2f(h.z), gw = bf2f(h.w);
        s2 += gx * gx + gy * gy + gz * gz + gw * gw;
        *(ushort4*)(zrow + fidx * 4) = h;  // global: linear
        // LDS: 16B chunk c = fidx>>1 goes to slot c^(v&7); 8B half = fidx&1
        int addr = (v << 8) + ((((fidx >> 1) ^ (v & 7))) << 4) + ((fidx & 1) << 3);
        *(ushort4*)((char*)zlds + addr) = h;
    }
    s2 += __shfl_xor(s2, 1); s2 += __shfl_xor(s2, 2); s2 += __shfl_xor(s2, 4);
    float s2s = s2 * K2F;
    if (s == 0) { sqv[(i << 5) + v] = s2s; sq_sh[v] = s2s; }
    __syncthreads();

    if (t < 64) {   // wave 0: E_ii row sums
        int lq = t & 31, kh = t >> 5, sx = lq & 7;
        f32x16 acc;
#pragma unroll
        for (int r = 0; r < 16; ++r) acc[r] = 0.f;
#pragma unroll
        for (int ks = 0; ks < 8; ++ks) {
            int off = (lq << 8) + (((2 * ks + kh) ^ sx) << 4);
            short8 av = *(const short8*)((char*)zlds + off);
            acc = __builtin_amdgcn_mfma_f32_32x32x16_bf16(av, av, acc, 0, 0, 0);
        }
        float sql = sq_sh[lq];
        float ssum = 0.f;
#pragma unroll
        for (int r = 0; r < 16; ++r) {
            int m = (r & 3) + 8 * (r >> 2) + 4 * kh;
            float d2 = fmaxf(sq_sh[m] + sql - C2F * acc[r], EPS2);
            ssum += exp2raw(FSQRT(d2));
        }
        ssum += __shfl_xor(ssum, 32);
        if (t < 32) diagsum[(i << 5) + lq] = ssum;
    }
}

// ---------------------------------------------------------------------------
// K2 (pair): 2x4 group tiles. Tile t0 -> (jg, ip): start(jg) = jg^2 + jg,
// ip in [0, 2jg+2); i0 = 2*ip, jbase = 4*jg. Stages 6 panels (2 i + 4 j,
// 48 KB) via global_load_lds (linear LDS dest, XOR swizzle on the per-lane
// GLOBAL source; same involution on the ds_read side). 512 threads, 8 waves;
// wave w owns pair (i = i0 + (w>>2), j = jbase + (w&3)) when j > i:
// dual MFMA (acc = Zi.Zj^T col stats in-lane; acc2 = Zj.Zi^T row stats
// in-lane), slimmed exp2 epilogue, bitonic rank-select ->
// Dmat[i][j] = Dmat[j][i]. 3 blocks/CU x 8 waves = 24 waves/CU.
// NOTE: no min-waves launch-bounds arg — R17 showed pinning VGPRs to 32
// spills acc/acc2 to scratch (84 MB WRITE_SIZE). Natural allocation ~48-60.
// ---------------------------------------------------------------------------
__global__ __launch_bounds__(512) void pair_kernel(const unsigned short* __restrict__ Zn,
                                                   const float* __restrict__ sqv,
                                                   const float* __restrict__ diagsum,
                                                   const int* __restrict__ tgt,
                                                   float* __restrict__ Dmat) {
    // unrank t0 -> (jg, ip): start(jg) = jg^2 + jg
    int t0 = blockIdx.x;
    int jg = (int)((sqrtf(4.f * (float)t0 + 1.f) - 1.f) * 0.5f);
    while (jg > 0 && t0 < jg * jg + jg) --jg;
    while (t0 >= (jg + 1) * (jg + 1) + (jg + 1)) ++jg;
    int ip = t0 - (jg * jg + jg);          // 0 .. 2jg+1
    int i0 = ip * 2;
    int jbase = jg * 4;

    extern __shared__ unsigned short lds[];   // 6 * 4096 ushort = 48 KB

    int t = threadIdx.x;
    int w = t >> 6;          // 0..7
    int lane = t & 63;
    int slot = lane & 15;
    int rhi = lane >> 4;

    // ---- staging: 48 segs of 1 KB; wave w owns segs [w*6, w*6+6) ----
#pragma unroll
    for (int k = 0; k < 6; ++k) {
        int seg = w * 6 + k;
        int panel = seg >> 3;              // 0..5
        int row = ((seg & 7) << 2) | rhi;  // 0..31
        int vec = (panel < 2) ? (i0 + panel) : (jbase + panel - 2);
        const unsigned short* gsrc =
            Zn + ((size_t)vec << 12) + (row << 7) + ((slot ^ (row & 7)) << 3);
        unsigned short* ldst = lds + seg * 512;
        __builtin_amdgcn_global_load_lds((const GLOBAL_AS void*)(const void*)gsrc,
                                         (LDS_AS void*)(void*)ldst, 16, 0, 0);
    }
    __syncthreads();

    int i = i0 + (w >> 2);
    int j = jbase + (w & 3);
    if (j <= i) return;       // idle waves on diagonal tiles; no more barriers

    const unsigned short* Pi = lds + (w >> 2) * 4096;
    const unsigned short* Pj = lds + (2 + (w & 3)) * 4096;
    int lq = lane & 31;
    int kh = lane >> 5;
    int sx = lq & 7;

    f32x16 acc, acc2;
#pragma unroll
    for (int r = 0; r < 16; ++r) { acc[r] = 0.f; acc2[r] = 0.f; }

#pragma unroll
    for (int ks = 0; ks < 8; ++ks) {
        int off = (lq << 7) + (((2 * ks + kh) ^ sx) << 3);
        short8 av = *(const short8*)(Pi + off);
        short8 bv = *(const short8*)(Pj + off);
        acc  = __builtin_amdgcn_mfma_f32_32x32x16_bf16(av, bv, acc, 0, 0, 0);
        acc2 = __builtin_amdgcn_mfma_f32_32x32x16_bf16(bv, av, acc2, 0, 0, 0);
    }

    // ---- slimmed epilogue ----
    float sqi_l = sqv[(i << 5) + lq];      // pre-scaled by K2F
    float sqj_l = sqv[(j << 5) + lq];
    float di = diagsum[(i << 5) + lq];
    float dj = diagsum[(j << 5) + lq];

    float sab[16], sba[16];
#pragma unroll
    for (int r = 0; r < 16; ++r) {
        int m = (r & 3) + 8 * (r >> 2) + 4 * kh;
        sab[r] = __shfl(sqi_l, m) + sqj_l;
        sba[r] = __shfl(sqj_l, m) + sqi_l;
    }

    float csum = 0.f, cmin = INFINITY, rsum = 0.f, rmin = INFINITY;
#pragma unroll
    for (int r = 0; r < 16; ++r) {
        float d2a = fmaxf(sab[r] - C2F * acc[r], EPS2);    // E[m][lq]
        float ea = exp2raw(FSQRT(d2a));
        csum += ea; cmin = fminf(cmin, ea);
        float d2b = fmaxf(sba[r] - C2F * acc2[r], EPS2);   // E[lq][m]
        float eb = exp2raw(FSQRT(d2b));
        rsum += eb; rmin = fminf(rmin, eb);
    }
    csum += __shfl_xor(csum, 32);
    cmin = fminf(cmin, __shfl_xor(cmin, 32));
    rsum += __shfl_xor(rsum, 32);
    rmin = fminf(rmin, __shfl_xor(rmin, 32));

    float aval = rmin / (di + rsum);
    float cval = cmin / (dj + csum);

    // bitonic ascending sort per 32-lane half: half0 = a, half1 = c
    float v = (lane < 32) ? aval : cval;
#pragma unroll
    for (int k = 2; k <= 32; k <<= 1) {
#pragma unroll
        for (int mm = k >> 1; mm >= 1; mm >>= 1) {
            float o = __shfl_xor(v, mm);
            bool asc = ((lq & k) == 0);
            bool upper = (lq & mm) != 0;
            float mn = fminf(v, o), mx = fmaxf(v, o);
            v = (asc == upper) ? mx : mn;
        }
    }
    // ascending: 3rd largest at lane 29, 6th at lane 26 (per half)
    float ta3 = __shfl(v, 29), ta6 = __shfl(v, 26);
    float tc3 = __shfl(v, 61), tc6 = __shfl(v, 58);

    if (lane == 0) {
        float v_same = fmaxf(ta6, tc6);
        float v_diff = fminf(ta3, tc3);
        float val = (tgt[i] == tgt[j]) ? v_same : v_diff;
        Dmat[i * B + j] = val;
        Dmat[j * B + i] = val;
    }
}

// ---------------------------------------------------------------------------
// K3 (final): 1024 threads; 8 threads per row i scan 16 cols each, reduce
// via shfl, then block-reduce the 128 row terms.
// ---------------------------------------------------------------------------
__global__ __launch_bounds__(1024) void final_kernel(const float* __restrict__ Dmat,
                                                     const int* __restrict__ tgt,
                                                     float* __restrict__ out) {
    int t = threadIdx.x;
    int i = t >> 3;          // row 0..127
    int c = t & 7;           // col chunk
    int ti = tgt[i];
    float ap = -INFINITY, an = INFINITY;
#pragma unroll
    for (int k = 0; k < 16; ++k) {
        int jj = c * 16 + k;
        float v = (jj == i) ? 0.f : Dmat[jj * B + i];   // D symmetric
        if (tgt[jj] == ti) ap = fmaxf(ap, v);
        else an = fminf(an, v);
    }
    ap = fmaxf(ap, __shfl_xor(ap, 1)); an = fminf(an, __shfl_xor(an, 1));
    ap = fmaxf(ap, __shfl_xor(ap, 2)); an = fminf(an, __shfl_xor(an, 2));
    ap = fmaxf(ap, __shfl_xor(ap, 4)); an = fminf(an, __shfl_xor(an, 4));

    __shared__ float red[128];
    if (c == 0) {
        float term = ap - an + MARGINF;
        red[i] = term > 0.f ? term : 0.f;
    }
    __syncthreads();
    if (t < 64) {
        float r0 = red[t] + red[t + 64];
        r0 += __shfl_down(r0, 32); r0 += __shfl_down(r0, 16);
        r0 += __shfl_down(r0, 8);  r0 += __shfl_down(r0, 4);
        r0 += __shfl_down(r0, 2);  r0 += __shfl_down(r0, 1);
        if (t == 0) out[0] = r0 / (float)B;
    }
}

// ---------------------------------------------------------------------------
extern "C" void kernel_launch(void* const* d_in, const int* in_sizes, int n_in,
                              void* d_out, int out_size, void* d_ws, size_t ws_size,
                              hipStream_t stream) {
    const float* X = (const float*)d_in[0];   // (128, 32, 128) f32
    const int* tgt = (const int*)d_in[1];     // (128,) int
    float* out = (float*)d_out;

    // ws: Zn bf16 1MB | sqv 16KB | diagsum 16KB | Dmat 64KB
    unsigned short* Zn = (unsigned short*)d_ws;
    float* sqv = (float*)(Zn + (size_t)NV * Dm);
    float* diagsum = sqv + NV;
    float* Dmat = diagsum + NV;

    prep_kernel<<<B, 256, 0, stream>>>(X, Zn, sqv, diagsum);
    pair_kernel<<<NTILE, 512, 6 * 4096 * sizeof(unsigned short), stream>>>(
        Zn, sqv, diagsum, tgt, Dmat);
    final_kernel<<<1, 1024, 0, stream>>>(Dmat, tgt, out);
}